// Round 11
// baseline (1630.831 us; speedup 1.0000x reference)
//
#include <hip/hip_runtime.h>

// LIF scan: B=16, S=256, H=128, N=64. T = S*H = 32768 sequential steps per
// (b,n) chain; 1024 chains. Bit-exact with the numpy fp32 sequential
// reference (hard thresholds on rounded sums). Chain form (proven bit-exact
// R1..R10, absmax=0):
//     s' = prev ? x : fl(s + x);  prev' = s' > th
//
// R10 post-mortem (554 us): writers concentrated on 32 CUs hit the per-CU
// store limit (~6.3 B/cyc/CU -> 484 GB/s); the chain stalled on ring
// backpressure. Fix: spread writes across ~250 CUs via checkpoint/replay
// writers gated by LLC flags.
//
// R9's version of this deadlocked because its grid exceeded residency.
// R11 makes the spin provably safe by CAPACITY: 496 blocks x 256 thr,
// 69.7 KB LDS -> exactly 2 blocks/CU (139<=160 KB), launch_bounds(256,2);
// grid 496 <= 512 resident slots -> every block is resident -> flag spins
// cannot deadlock (no dispatch-order assumption beyond full residency).
//   blocks 0..15   : chain blocks. wave0 = chain (4-deep pipelined LDS x
//                    reads, R10-proven); wave1 = x producer; wave2 =
//                    checkpoint publisher (agent stores + vmcnt(0) + flag);
//                    wave3 idle. Intra-block generation flags (R10-proven).
//   blocks 16..495 : 4 writer waves each. Task tau in [0,4096) = (srow,b)
//                    row-major across batches; spin on agent flag, replay
//                    128 steps from checkpoint (bit-exact, R5..R8-proven),
//                    two-stage LDS transpose, coalesced 1 KB stores.

namespace {
constexpr int kB = 16;
constexpr int kS = 256;
constexpr int kH = 128;
constexpr int kN = 64;
constexpr int kT = kS * kH;                 // 32768
constexpr long kPerB = (long)kS * kN * kH;  // 2,097,152 per batch per tensor
constexpr int kChainBlocks = kB;
constexpr int kWriterBlocks = 480;
constexpr int kWriterWaves = kWriterBlocks * 4;  // 1920
constexpr int kTasks = kB * kS;                  // 4096 rows
constexpr size_t kWsS = (size_t)kB * kS * kN * sizeof(float);          // 1 MB
constexpr size_t kWsM = (size_t)kB * kS * sizeof(unsigned long long);  // 32 KB
constexpr size_t kWsF = (size_t)kTasks * sizeof(int);                  // 16 KB
}

typedef float v4f __attribute__((ext_vector_type(4)));

__device__ __forceinline__ int opaque_vgpr_zero() {
  int z;
  asm volatile("v_mov_b32 %0, 0" : "=v"(z));
  return z;
}
__device__ __forceinline__ int ld_wg(const int* p) {
  return __hip_atomic_load(p, __ATOMIC_RELAXED, __HIP_MEMORY_SCOPE_WORKGROUP);
}
__device__ __forceinline__ void st_wg(int* p, int v) {
  __hip_atomic_store(p, v, __ATOMIC_RELAXED, __HIP_MEMORY_SCOPE_WORKGROUP);
}
#define SPIN_WG(ptr, want) \
  while (ld_wg(ptr) != (want)) __builtin_amdgcn_s_sleep(1)

__global__ __launch_bounds__(256, 2) void lif_r11_kernel(
    const float* __restrict__ x, const float* __restrict__ thresh,
    const float* __restrict__ acc0, float* ckpt_s,
    unsigned long long* ckpt_m, int* flags, float* __restrict__ out) {
  const int bid = blockIdx.x;
  const int tid = threadIdx.x;
  const int wid = tid >> 6;
  const int lane = tid & 63;
  const int l32 = lane & 31;

  __shared__ union SH {
    struct {                                 // chain blocks
      alignas(16) float xring[4][kH];        // 2 KB
      alignas(16) float mail_s[4][kN];       // 1 KB
      unsigned long long mail_m[4];
    } p1;
    struct {                                 // writer blocks
      alignas(16) float ovt[4][kN][68];      // 69.6 KB (per-wave 17.4 KB)
    } wr;
  } sh;
  __shared__ int xflag[4], xrel[4], mflag[4], mrel[4];  // outside union

  if (bid < kChainBlocks) {
    // ========================== chain block ==========================
    const int b = bid;
    if (tid < 4) {
      xflag[tid] = 0;        // producer sets t+1 when x row t staged
      xrel[tid] = tid - 3;   // chain sets t+1 when x row t consumed
      mflag[tid] = 0;        // chain sets t+1 when mail row t written
      mrel[tid] = tid - 3;   // publisher sets t+1 when mail row t consumed
    }
    __syncthreads();  // all 4 waves of this block

    if (wid == 0) {
      // ---- chain wave: 64 chains, 4-deep pipelined x reads (R10) ----
      const float th = thresh[lane];
      float s = acc0[b * kN + lane];
      bool prev = false;

      SPIN_WG(&xflag[0], 1);
      v4f p0 = *(const v4f*)&sh.p1.xring[0][0];
      v4f p1 = *(const v4f*)&sh.p1.xring[0][4];
      v4f p2 = *(const v4f*)&sh.p1.xring[0][8];
      v4f p3 = *(const v4f*)&sh.p1.xring[0][12];

      for (int t = 0; t < kS; ++t) {
        if (t + 1 < kS) SPIN_WG(&xflag[(t + 1) & 3], t + 2);
        SPIN_WG(&mrel[t & 3], t - 3);  // mail slot free
        sh.p1.mail_s[t & 3][lane] = s;  // state ENTERING row t
        {
          const unsigned long long m = __ballot(prev);
          if (lane == 0) sh.p1.mail_m[t & 3] = m;
        }
        asm volatile("s_waitcnt lgkmcnt(0)" ::: "memory");
        if (lane == 0) st_wg(&mflag[t & 3], t + 1);

        const float* bc = sh.p1.xring[t & 3];
        const float* bn = sh.p1.xring[(t + 1) & 3];
#pragma unroll
        for (int q = 0; q < 32; ++q) {
#pragma unroll
          for (int j = 0; j < 4; ++j) {
            const float xt = p0[j];
            const float u = s + xt;  // dep-chain op 1
            s = prev ? xt : u;       // dep-chain op 2
            prev = s > th;           // off-chain
          }
          p0 = p1; p1 = p2; p2 = p3;  // rotation renames (unrolled)
          p3 = (q < 28) ? *(const v4f*)&bc[(q + 4) * 4]
                        : *(const v4f*)&bn[(q - 28) * 4];  // 16-step lead
        }
        if (lane == 0) st_wg(&xrel[t & 3], t + 1);  // x slot consumed
      }
    } else if (wid == 1) {
      // ---- producer wave: global x -> xring (2-row register lead) ----
      const v4f* __restrict__ xg4 = (const v4f*)(x + (long)b * kT);
      v4f va = xg4[0 * 32 + l32];
      v4f vb = xg4[1 * 32 + l32];
      for (int t = 0; t < kS; ++t) {
        SPIN_WG(&xrel[t & 3], t - 3);
        *(v4f*)&sh.p1.xring[t & 3][l32 * 4] = va;  // lanes 32..63 duplicate
        asm volatile("s_waitcnt lgkmcnt(0)" ::: "memory");
        if (lane == 0) st_wg(&xflag[t & 3], t + 1);
        va = vb;
        if (t + 2 < kS) vb = xg4[(t + 2) * 32 + l32];
      }
    } else if (wid == 2) {
      // ---- publisher wave: mail -> LLC checkpoints + flags ----
      float* cs = ckpt_s + (long)b * kS * kN;
      unsigned long long* cm = ckpt_m + (long)b * kS;
      for (int t = 0; t < kS; ++t) {
        SPIN_WG(&mflag[t & 3], t + 1);
        const float sv = sh.p1.mail_s[t & 3][lane];
        const unsigned long long m = sh.p1.mail_m[t & 3];
        __hip_atomic_store(&cs[(long)t * kN + lane], sv, __ATOMIC_RELAXED,
                           __HIP_MEMORY_SCOPE_AGENT);
        if (lane == 0)
          __hip_atomic_store(&cm[t], m, __ATOMIC_RELAXED,
                             __HIP_MEMORY_SCOPE_AGENT);
        asm volatile("s_waitcnt vmcnt(0)" ::: "memory");  // data at LLC
        if (lane == 0) {
          __hip_atomic_store(&flags[b * kS + t], 1, __ATOMIC_RELAXED,
                             __HIP_MEMORY_SCOPE_AGENT);
          st_wg(&mrel[t & 3], t + 1);
        }
      }
    }
    // wave 3: idle
  } else {
    // ========================== writer blocks ==========================
    const int W = (bid - kChainBlocks) * 4 + wid;  // 0..1919
    const float th = thresh[lane];
    float(*ovt)[68] = sh.wr.ovt[wid];
    float* __restrict__ outs = out;
    float* __restrict__ spks = out + (long)kB * kPerB;

    for (int tau = W; tau < kTasks; tau += kWriterWaves) {
      const int srow = tau >> 4;  // row-major across batches: early rows
      const int b = tau & 15;     // of every batch are available first
      // x loads issued BEFORE the spin (input memory, always valid)
      const v4f* __restrict__ xr4 =
          (const v4f*)(x + (long)b * kT + srow * kH) + opaque_vgpr_zero();
      v4f xb[32];
#pragma unroll
      for (int i = 0; i < 32; ++i) xb[i] = xr4[i];

      const int* fp = &flags[b * kS + srow];
      while (__hip_atomic_load(fp, __ATOMIC_ACQUIRE,
                               __HIP_MEMORY_SCOPE_AGENT) != 1)
        __builtin_amdgcn_s_sleep(8);

      float s = __hip_atomic_load(&ckpt_s[((long)b * kS + srow) * kN + lane],
                                  __ATOMIC_RELAXED, __HIP_MEMORY_SCOPE_AGENT);
      const unsigned long long m =
          __hip_atomic_load(&ckpt_m[b * kS + srow], __ATOMIC_RELAXED,
                            __HIP_MEMORY_SCOPE_AGENT);
      bool prev = (m >> lane) & 1ULL;

      float* __restrict__ obase = outs + (long)b * kPerB + (long)srow * (kN * kH);
      float* __restrict__ sbase = spks + (long)b * kPerB + (long)srow * (kN * kH);

      // ---- stage A: steps 0..63 (h in [0,64)) ----
#pragma unroll
      for (int q = 0; q < 16; ++q) {
        v4f o;
#pragma unroll
        for (int j = 0; j < 4; ++j) {
          const float xt = xb[q][j];
          const float u = s + xt;
          s = prev ? xt : u;  // bit-identical replay
          prev = s > th;
          o[j] = prev ? s : 0.0f;
        }
        *(v4f*)&ovt[lane][q * 4] = o;
      }
      asm volatile("s_waitcnt lgkmcnt(0)" ::: "memory");  // cross-lane LDS
#pragma unroll
      for (int i = 0; i < 16; ++i) {
        const int n = 4 * i + (lane >> 4);
        const int hh0 = (lane & 15) * 4;
        const v4f o = *(const v4f*)&ovt[n][hh0];
        v4f f;
#pragma unroll
        for (int j = 0; j < 4; ++j) f[j] = o[j] > 0.0f ? 1.0f : 0.0f;
        *(v4f*)(obase + n * kH + hh0) = o;  // 16 full lines per wave instr
        *(v4f*)(sbase + n * kH + hh0) = f;
      }
      asm volatile("s_waitcnt lgkmcnt(0)" ::: "memory");  // reads done (reuse)

      // ---- stage B: steps 64..127 (h in [64,128)) ----
#pragma unroll
      for (int q = 16; q < 32; ++q) {
        v4f o;
#pragma unroll
        for (int j = 0; j < 4; ++j) {
          const float xt = xb[q][j];
          const float u = s + xt;
          s = prev ? xt : u;
          prev = s > th;
          o[j] = prev ? s : 0.0f;
        }
        *(v4f*)&ovt[lane][(q - 16) * 4] = o;
      }
      asm volatile("s_waitcnt lgkmcnt(0)" ::: "memory");
#pragma unroll
      for (int i = 0; i < 16; ++i) {
        const int n = 4 * i + (lane >> 4);
        const int hh0 = (lane & 15) * 4;
        const v4f o = *(const v4f*)&ovt[n][hh0];
        v4f f;
#pragma unroll
        for (int j = 0; j < 4; ++j) f[j] = o[j] > 0.0f ? 1.0f : 0.0f;
        *(v4f*)(obase + n * kH + 64 + hh0) = o;
        *(v4f*)(sbase + n * kH + 64 + hh0) = f;
      }
      asm volatile("s_waitcnt lgkmcnt(0)" ::: "memory");
    }
  }
}

// ---------------------------------------------------------------------------
// Fallback (ws too small): R4's passing fused kernel (1060 us).
// ---------------------------------------------------------------------------
__global__ __launch_bounds__(128) void lif_fused_kernel(
    const float* __restrict__ x, const float* __restrict__ thresh,
    const float* __restrict__ acc0, float* __restrict__ out) {
  const int bid = blockIdx.x;
  const int b = bid >> 2;
  const int ng = bid & 3;
  const int tid = threadIdx.x;
  const int wave = tid >> 6;
  const int lane = tid & 63;
  __shared__ float buf[2][kH][64];
  const float* __restrict__ xb = x + (long)b * kT;
  float* __restrict__ outs_g = out + (long)b * kPerB + (long)(ng * 16) * kH;
  float* __restrict__ spks_g = outs_g + (long)kB * kPerB;
  if (wave == 0) {
    const int n = lane & 15;
    const float th = thresh[ng * 16 + n];
    float s = acc0[b * kN + ng * 16 + n];
    bool prev = false;
    for (int r = 0; r < kS + 1; ++r) {
      if (r < kS) {
        float* __restrict__ bk = &buf[r & 1][0][lane];
        const float* __restrict__ xr = xb + r * kH;
#pragma unroll
        for (int k = 0; k < kH; ++k) {
          const float xt = xr[k];
          const float u = s + xt;
          s = prev ? xt : u;
          prev = s > th;
          bk[k * 64] = s;
        }
      }
      __syncthreads();
    }
  } else {
    const int n = lane >> 2;
    const int hg = lane & 3;
    const float th = thresh[ng * 16 + n];
    for (int r = 0; r < kS + 1; ++r) {
      if (r > 0) {
        const int rr = r - 1;
        const float(*bk)[64] = buf[rr & 1];
        float* __restrict__ orow = outs_g + (long)rr * (kN * kH) + n * kH;
        float* __restrict__ srow = spks_g + (long)rr * (kN * kH) + n * kH;
#pragma unroll
        for (int i = 0; i < 8; ++i) {
          const int hh = hg * 4 + i * 16;
          v4f ovv, sv;
#pragma unroll
          for (int j = 0; j < 4; ++j) {
            const float v = bk[hh + j][n];
            const bool sp = v > th;
            ovv[j] = sp ? v : 0.0f;
            sv[j] = sp ? 1.0f : 0.0f;
          }
          *(v4f*)(orow + hh) = ovv;
          *(v4f*)(srow + hh) = sv;
        }
      }
      __syncthreads();
    }
  }
}

// ---------------------------------------------------------------------------
extern "C" void kernel_launch(void* const* d_in, const int* in_sizes, int n_in,
                              void* d_out, int out_size, void* d_ws, size_t ws_size,
                              hipStream_t stream) {
  const float* inputs = (const float*)d_in[0];    // [B,S,H] fp32
  const float* threshes = (const float*)d_in[1];  // [N] fp32
  const float* acc0 = (const float*)d_in[2];      // [B,N] fp32
  float* out = (float*)d_out;

  if (ws_size >= kWsS + kWsM + kWsF) {
    float* ckpt_s = (float*)d_ws;
    unsigned long long* ckpt_m = (unsigned long long*)((char*)d_ws + kWsS);
    int* flags = (int*)((char*)d_ws + kWsS + kWsM);
    // 496 blocks x 256 thr, 69.7 KB LDS -> 2 blocks/CU, grid <= 512 resident
    // slots: whole grid co-resident; intra-grid flag spins are safe.
    lif_r11_kernel<<<kChainBlocks + kWriterBlocks, 256, 0, stream>>>(
        inputs, threshes, acc0, ckpt_s, ckpt_m, flags, out);
  } else {
    lif_fused_kernel<<<kB * 4, 128, 0, stream>>>(inputs, threshes, acc0, out);
  }
}

// Round 12
// 700.040 us; speedup vs baseline: 2.3296x; 2.3296x over previous
//
#include <hip/hip_runtime.h>

// LIF scan: B=16, S=256, H=128, N=64. T = S*H = 32768 sequential steps per
// (b,n) chain; 1024 chains. Bit-exact with the numpy fp32 sequential
// reference (hard thresholds on rounded sums). Chain form (proven bit-exact
// R1..R11, absmax=0):
//     s' = prev ? x : fl(s + x);  prev' = s' > th
//
// R11 post-mortem (1425 us): cross-block LLC flags + per-row agent-store
// vmcnt(0) publisher + 1920 ACQUIRE-polling waves destroyed the pipeline.
// Reverting to R10's all-intra-block skeleton (554 us), whose limit was
// write concentration: 484 GB/s / 32 CUs = 6.3 B/cyc/CU vs the repeatedly
// measured device write wall ~1.07 TB/s (R1/R6/R7/R8).
//
// R12 changes vs R10:
//  1) 128 blocks (= batch x 8-neuron group) instead of 32 -> writers live on
//     128 CUs -> aggregate write capability ~1.9 TB/s > device wall.
//  2) x supply via per-lane load + readlane: xv = x[c*64+lane] (one coalesced
//     256 B load per 64 steps, only 4 scalar VGPRs of buffering -> allocator
//     cannot collapse the 256-step lookahead), step value broadcast with
//     __builtin_amdgcn_readlane(xv, k) with literal k in the unrolled loop.
//     Kills the producer wave, the x-ring, and ALL LDS reads in the chain.
//  3) s-ring depth 8, 8 writer waves, workgroup-scope LDS generation flags
//     only (R10-proven). No cross-block communication of any kind.
// Chain wave duplicates each 8-chain group across 8 lane-groups; only lanes
// 0..7 store to the s-ring (predicated, conflict-free).

namespace {
constexpr int kB = 16;
constexpr int kS = 256;
constexpr int kH = 128;
constexpr int kN = 64;
constexpr int kT = kS * kH;                 // 32768
constexpr long kPerB = (long)kS * kN * kH;  // 2,097,152 per batch per tensor
constexpr int kNB = 8;                      // neurons per block
constexpr int kGroups = kN / kNB;           // 8 blocks per batch
constexpr int kWr = 8;                      // writer waves per block
constexpr int kDepth = 8;                   // s-ring slots
}

typedef float v4f __attribute__((ext_vector_type(4)));

__device__ __forceinline__ int ld_wg(const int* p) {
  return __hip_atomic_load(p, __ATOMIC_RELAXED, __HIP_MEMORY_SCOPE_WORKGROUP);
}
__device__ __forceinline__ void st_wg(int* p, int v) {
  __hip_atomic_store(p, v, __ATOMIC_RELAXED, __HIP_MEMORY_SCOPE_WORKGROUP);
}
#define SPIN_WG(ptr, want) \
  while (ld_wg(ptr) != (want)) __builtin_amdgcn_s_sleep(1)

// One 64-step chunk fed from register xv via readlane (literal lane index
// after unroll). Writes 16 v4f of raw s into the s-ring row (lanes 0..7).
__device__ __forceinline__ void chunk64(float xv, float* __restrict__ sw,
                                        int qb, float& s, bool& prev,
                                        float th, int lane) {
#pragma unroll
  for (int q = 0; q < 16; ++q) {
    v4f sq;
#pragma unroll
    for (int j = 0; j < 4; ++j) {
      const float xt = __int_as_float(
          __builtin_amdgcn_readlane(__float_as_int(xv), q * 4 + j));
      const float u = s + xt;  // dep-chain op 1
      s = prev ? xt : u;       // dep-chain op 2
      prev = s > th;           // off-chain
      sq[j] = s;               // raw post-add value (pre-reset)
    }
    if (lane < kNB) *(v4f*)(sw + (qb + q) * 4) = sq;  // exec-masked b128
  }
}

__global__ __launch_bounds__(64 * (1 + kWr)) void lif_r12_kernel(
    const float* __restrict__ x, const float* __restrict__ thresh,
    const float* __restrict__ acc0, float* __restrict__ out) {
  const int bid = blockIdx.x;
  const int b = bid >> 3;        // batch
  const int g = bid & 7;         // neuron group
  const int n0 = g * kNB;        // first neuron of this block
  const int tid = threadIdx.x;
  const int wid = tid >> 6;
  const int lane = tid & 63;

  // rows padded to 132 floats (528 B): 16B-aligned b128, banks advance by 4
  // per neuron row -> lanes 0..7 write 32 distinct banks.
  __shared__ alignas(16) float sring[kDepth][kNB][132];  // 33.8 KB
  __shared__ float lth[kNB];
  __shared__ int sflag[kDepth], srel[kDepth];

  if (tid < kNB) lth[tid] = thresh[n0 + tid];
  if (tid < kDepth) {
    sflag[tid] = 0;               // chain sets t+1 when row t staged
    srel[tid] = tid - (kDepth - 1);  // writer sets t+1 when row t consumed
  }
  __syncthreads();  // the only barrier; executed uniformly by all 9 waves

  if (wid == 0) {
    // ===================== chain wave (the scan) =====================
    const int nl = lane & (kNB - 1);  // chain within group (8x duplicated)
    const float th = lth[nl];
    float s = acc0[b * kN + n0 + nl];
    bool prev = false;
    const float* __restrict__ xg = x + (long)b * kT;

    // 4 rotating scalar x buffers: chunk c lives in xv_{c&3}; reloaded with
    // chunk c+4 right after consumption -> 256-step (~3000 cyc) lookahead.
    float xv0 = xg[0 * 64 + lane];
    float xv1 = xg[1 * 64 + lane];
    float xv2 = xg[2 * 64 + lane];
    float xv3 = xg[3 * 64 + lane];

    for (int i = 0; i < 128; ++i) {  // 2 rows (4 chunks) per iteration
      const int c4 = 4 * i;
      // ---- row 2i (chunks c4, c4+1) ----
      int t = 2 * i;
      SPIN_WG(&srel[t & 7], t - 7);
      float* sw = &sring[t & 7][nl][0];
      chunk64(xv0, sw, 0, s, prev, th, lane);
      chunk64(xv1, sw, 16, s, prev, th, lane);
      asm volatile("s_waitcnt lgkmcnt(0)" ::: "memory");
      if (lane == 0) st_wg(&sflag[t & 7], t + 1);
      {
        const int ca = c4 + 4 < 512 ? c4 + 4 : 511;
        const int cb = c4 + 5 < 512 ? c4 + 5 : 511;
        xv0 = xg[ca * 64 + lane];  // in flight for ~2 rows
        xv1 = xg[cb * 64 + lane];
      }
      // ---- row 2i+1 (chunks c4+2, c4+3) ----
      t = 2 * i + 1;
      SPIN_WG(&srel[t & 7], t - 7);
      sw = &sring[t & 7][nl][0];
      chunk64(xv2, sw, 0, s, prev, th, lane);
      chunk64(xv3, sw, 16, s, prev, th, lane);
      asm volatile("s_waitcnt lgkmcnt(0)" ::: "memory");
      if (lane == 0) st_wg(&sflag[t & 7], t + 1);
      {
        const int cc = c4 + 6 < 512 ? c4 + 6 : 511;
        const int cd = c4 + 7 < 512 ? c4 + 7 : 511;
        xv2 = xg[cc * 64 + lane];
        xv3 = xg[cd * 64 + lane];
      }
    }
  } else {
    // ======================= writer waves (8x) =======================
    const int w = wid - 1;
    float* __restrict__ obat = out + (long)b * kPerB;
    float* __restrict__ sbat = obat + (long)kB * kPerB;
    const int h0 = (lane & 31) * 4;
    const int np = lane >> 5;

    for (int t = w; t < kS; t += kWr) {
      SPIN_WG(&sflag[t & 7], t + 1);
      const float(*sl)[132] = sring[t & 7];
      float* __restrict__ orow = obat + (long)t * (kN * kH) + (long)n0 * kH;
      float* __restrict__ srow = sbat + (long)t * (kN * kH) + (long)n0 * kH;
#pragma unroll
      for (int i = 0; i < 4; ++i) {
        const int nl = 2 * i + np;                // 0..7
        const v4f o = *(const v4f*)&sl[nl][h0];   // ds_read_b128
        const float thn = lth[nl];
        v4f ov, fv;
#pragma unroll
        for (int j = 0; j < 4; ++j) {
          const bool sp = o[j] > thn;  // same compare as the chain
          ov[j] = sp ? o[j] : 0.0f;
          fv[j] = sp ? 1.0f : 0.0f;
        }
        *(v4f*)(orow + nl * kH + h0) = ov;  // 1 KB contiguous per wave instr
        *(v4f*)(srow + nl * kH + h0) = fv;  // 1 KB contiguous per wave instr
      }
      // release once LDS reads are complete; global stores drain in the
      // background and are never waited on.
      asm volatile("s_waitcnt lgkmcnt(0)" ::: "memory");
      if (lane == 0) st_wg(&srel[t & 7], t + 1);
    }
  }
}

// ---------------------------------------------------------------------------
extern "C" void kernel_launch(void* const* d_in, const int* in_sizes, int n_in,
                              void* d_out, int out_size, void* d_ws, size_t ws_size,
                              hipStream_t stream) {
  const float* inputs = (const float*)d_in[0];    // [B,S,H] fp32
  const float* threshes = (const float*)d_in[1];  // [N] fp32
  const float* acc0 = (const float*)d_in[2];      // [B,N] fp32
  float* out = (float*)d_out;

  // 128 blocks = 16 batches x 8 neuron-groups; 9 waves per block
  // (1 chain + 8 writers). All sync is intra-block LDS generation flags
  // (G16-safe, R10-proven); writes spread across 128 CUs to reach the
  // ~1.07 TB/s device write wall.
  lif_r12_kernel<<<kB * kGroups, 64 * (1 + kWr), 0, stream>>>(
      inputs, threshes, acc0, out);
}